// Round 1
// 6752.092 us; speedup vs baseline: 3.0688x; 3.0688x over previous
//
#include <hip/hip_runtime.h>
#include <hip/hip_bf16.h>
#include <stdint.h>

// Problem constants: B=64, S=512, D=1024, H=1024, O=1024
#define BB   64
#define SS   512
#define DD   1024
#define HH   1024
#define TH3  3072   // 3*H
#define TCH  32     // timestep chunk for Gx precompute

using frag8 = __attribute__((ext_vector_type(8))) short;   // 8 bf16
using f32x4 = __attribute__((ext_vector_type(4))) float;

__device__ __forceinline__ void split_bf16(float v, short& hi, short& lo) {
    uint32_t u = __float_as_uint(v);
    uint32_t uh = u & 0xFFFF0000u;          // truncate to bf16
    float fl = v - __uint_as_float(uh);     // exact residual
    hi = (short)(uh >> 16);
    lo = (short)(__float_as_uint(fl) >> 16);
}

__device__ __forceinline__ float bf2f(unsigned short u) {
    union { uint32_t i; float f; } v;
    v.i = ((uint32_t)u) << 16;
    return v.f;
}

// ---------------------------------------------------------------------------
// W pre-transform: Wg [2048, 3072] fp32 -> Wt_hi/Wt_lo bf16 in MFMA B-fragment
// order. Fragment f = (jb*3 + g)*64 + kt covers k = kt*32 + quad*8 + j,
// n(col) = g*1024 + jb*16 + (lane&15). Stored as Wt[f*512 + lane*8 + j].
// kt 0..31 = x rows (0..1023), kt 32..63 = h rows (1024..2047).
// ---------------------------------------------------------------------------
__global__ __launch_bounds__(256) void prep_w(
    const float* __restrict__ Wg, short* __restrict__ Wt_hi,
    short* __restrict__ Wt_lo)
{
    int idx = blockIdx.x * 256 + threadIdx.x;   // 0 .. 786431
    int lane = idx & 63;
    int f = idx >> 6;            // 0..12287
    int kt = f & 63;
    int fg = f >> 6;
    int g = fg % 3;
    int jb = fg / 3;
    int krow = kt * 32 + (lane >> 4) * 8;
    int col = g * HH + jb * 16 + (lane & 15);
    size_t dst = (size_t)f * 512 + (size_t)lane * 8;
#pragma unroll
    for (int j = 0; j < 8; ++j) {
        float v = Wg[(size_t)(krow + j) * TH3 + col];
        short hi, lo;
        split_bf16(v, hi, lo);
        Wt_hi[dst + j] = hi;
        Wt_lo[dst + j] = lo;
    }
}

// ---------------------------------------------------------------------------
// Gx precompute: gx[tl, m, :] = x[m, t0+tl, :] @ Wg[0:1024, :] + bg
// Grid = TCH*64 blocks (jb fastest -> same-jb blocks share an XCD for W
// L2 reuse), 4 waves; wave w owns batch rows w*16..w*16+15, all 3 gates.
// This is the hoisted, fully-parallel half of the old per-step kernel.
// ---------------------------------------------------------------------------
__global__ __launch_bounds__(256) void gx_gemm(
    const short* __restrict__ Wt_hi, const short* __restrict__ Wt_lo,
    const float* __restrict__ x,        // [B, S, D] fp32
    const float* __restrict__ bg,       // [3H]
    float* __restrict__ gx,             // [TCH, B, 3H] fp32
    int t0)
{
    const int tid = threadIdx.x;
    const int lane = tid & 63;
    const int w = tid >> 6;
    const int jb = blockIdx.x & 63;
    const int tl = blockIdx.x >> 6;
    const int t = t0 + tl;
    const int m0 = w * 16;
    const int mrow = m0 + (lane & 15);
    const int kq = (lane >> 4) * 8;

    f32x4 accr = {0.f, 0.f, 0.f, 0.f};
    f32x4 accz = {0.f, 0.f, 0.f, 0.f};
    f32x4 accn = {0.f, 0.f, 0.f, 0.f};
    const size_t fbase = (size_t)jb * 3 * 64;
    const float* xrow = x + ((size_t)mrow * SS + t) * DD;

    for (int kt = 0; kt < 32; ++kt) {
        const float* xp = xrow + kt * 32 + kq;
        float xv[8];
        *(float4*)&xv[0] = *(const float4*)xp;
        *(float4*)&xv[4] = *(const float4*)(xp + 4);
        frag8 a_hi, a_lo;
#pragma unroll
        for (int j = 0; j < 8; ++j) {
            short hi, lo;
            split_bf16(xv[j], hi, lo);
            a_hi[j] = hi;
            a_lo[j] = lo;
        }
#pragma unroll
        for (int g = 0; g < 3; ++g) {
            size_t base = (fbase + (size_t)g * 64 + kt) * 512 + (size_t)lane * 8;
            frag8 b_hi = *(const frag8*)(Wt_hi + base);
            frag8 b_lo = *(const frag8*)(Wt_lo + base);
            f32x4 acc = (g == 0) ? accr : (g == 1) ? accz : accn;
            acc = __builtin_amdgcn_mfma_f32_16x16x32_bf16(a_hi, b_hi, acc, 0, 0, 0);
            acc = __builtin_amdgcn_mfma_f32_16x16x32_bf16(a_hi, b_lo, acc, 0, 0, 0);
            acc = __builtin_amdgcn_mfma_f32_16x16x32_bf16(a_lo, b_hi, acc, 0, 0, 0);
            if (g == 0) accr = acc; else if (g == 1) accz = acc; else accn = acc;
        }
    }

    const int col = jb * 16 + (lane & 15);
    const int rbase = m0 + (lane >> 4) * 4;
    const float b_r = bg[col];
    const float b_z = bg[HH + col];
    const float b_n = bg[2 * HH + col];
#pragma unroll
    for (int reg = 0; reg < 4; ++reg) {
        int m = rbase + reg;
        float* gp = gx + ((size_t)tl * BB + m) * TH3;
        gp[col] = accr[reg] + b_r;
        gp[HH + col] = accz[reg] + b_z;
        gp[2 * HH + col] = accn[reg] + b_n;
    }
}

// ---------------------------------------------------------------------------
// One GRU step, h-contribution only: gates = gx[tl] + h @ Wg[1024:2048, :].
// Grid = 256 blocks = 4 m-tiles x 64 jb (jb fastest -> same-jb same XCD).
// 4 waves K-split the 32 kt (8 each), partials reduced through LDS; the
// 256 threads then each own one of the 16x16 outputs for the epilogue.
// ---------------------------------------------------------------------------
__global__ __launch_bounds__(256) void gru_step_h(
    const short* __restrict__ Wt_hi, const short* __restrict__ Wt_lo,
    const float* __restrict__ gx,       // [TCH, B, 3H]
    const float* __restrict__ h_f,      // [B, H] fp32 (current)
    const short* __restrict__ h_hi,     // [B, H] bf16 hi (current)
    const short* __restrict__ h_lo,     // [B, H] bf16 lo (current)
    float* __restrict__ hn_f,           // [B, H] fp32 (next)
    short* __restrict__ hn_hi, short* __restrict__ hn_lo,
    __hip_bfloat16* __restrict__ hs,    // [B, S, H] bf16 history
    int t, int tl)
{
    __shared__ float red[12][256];      // [w*3+g][lane*4+reg]

    const int tid = threadIdx.x;
    const int lane = tid & 63;
    const int w = tid >> 6;
    const int jb = blockIdx.x & 63;
    const int mt = blockIdx.x >> 6;
    const int m0 = mt * 16;
    const int mrow = m0 + (lane & 15);
    const int kq = (lane >> 4) * 8;

    // Hoisted epilogue loads: issue before the MFMA loop so their latency
    // hides under compute. Thread tid owns output (lv=tid>>2, reg=tid&3).
    const int lv = tid >> 2;
    const int reg = tid & 3;
    const int ecol = jb * 16 + (lv & 15);
    const int em = m0 + ((lv >> 4) << 2) + reg;
    const float* gp = gx + ((size_t)tl * BB + em) * TH3 + ecol;
    const float gxr = gp[0];
    const float gxz = gp[HH];
    const float gxn = gp[2 * HH];
    const float hold = h_f[(size_t)em * HH + ecol];

    f32x4 accr = {0.f, 0.f, 0.f, 0.f};
    f32x4 accz = {0.f, 0.f, 0.f, 0.f};
    f32x4 accn = {0.f, 0.f, 0.f, 0.f};
    const size_t fbase = (size_t)jb * 3 * 64;
    const short* hrh = h_hi + (size_t)mrow * HH;
    const short* hrl = h_lo + (size_t)mrow * HH;

#pragma unroll
    for (int i = 0; i < 8; ++i) {
        const int kt = w * 8 + i;                  // this wave's K slice
        frag8 a_hi = *(const frag8*)(hrh + kt * 32 + kq);
        frag8 a_lo = *(const frag8*)(hrl + kt * 32 + kq);
#pragma unroll
        for (int g = 0; g < 3; ++g) {
            size_t base = (fbase + (size_t)g * 64 + 32 + kt) * 512 + (size_t)lane * 8;
            frag8 b_hi = *(const frag8*)(Wt_hi + base);
            frag8 b_lo = *(const frag8*)(Wt_lo + base);
            f32x4 acc = (g == 0) ? accr : (g == 1) ? accz : accn;
            acc = __builtin_amdgcn_mfma_f32_16x16x32_bf16(a_hi, b_hi, acc, 0, 0, 0);
            acc = __builtin_amdgcn_mfma_f32_16x16x32_bf16(a_hi, b_lo, acc, 0, 0, 0);
            acc = __builtin_amdgcn_mfma_f32_16x16x32_bf16(a_lo, b_hi, acc, 0, 0, 0);
            if (g == 0) accr = acc; else if (g == 1) accz = acc; else accn = acc;
        }
    }

    *(f32x4*)&red[w * 3 + 0][lane * 4] = accr;
    *(f32x4*)&red[w * 3 + 1][lane * 4] = accz;
    *(f32x4*)&red[w * 3 + 2][lane * 4] = accn;
    __syncthreads();

    // Cross-wave K reduction (stride-1 in tid: conflict-free).
    float rg = gxr + red[0][tid] + red[3][tid] + red[6][tid] + red[9][tid];
    float zg = gxz + red[1][tid] + red[4][tid] + red[7][tid] + red[10][tid];
    float ng = gxn + red[2][tid] + red[5][tid] + red[8][tid] + red[11][tid];

    float r = 1.f / (1.f + __expf(-rg));
    float z = 1.f / (1.f + __expf(-zg));
    float na = ng + r * hold;
    float n = 1.f - 2.f / (1.f + __expf(2.f * na));   // tanh(na)
    float hn = (1.f - z) * n + z * hold;

    hn_f[(size_t)em * HH + ecol] = hn;
    short hi, lo;
    split_bf16(hn, hi, lo);
    hn_hi[(size_t)em * HH + ecol] = hi;
    hn_lo[(size_t)em * HH + ecol] = lo;
    hs[((size_t)em * SS + t) * HH + ecol] = __float2bfloat16(hn);
}

// ---------------------------------------------------------------------------
// Output GEMM: out[B*S, O] = hs_bf16[B*S, H] @ Wc[H, O] + bc  (fp32 vector)
// ---------------------------------------------------------------------------
#define BM 128
#define BN 128
#define BK 8

__global__ __launch_bounds__(256) void out_gemm(
    const __hip_bfloat16* __restrict__ A, const float* __restrict__ Bm,
    const float* __restrict__ bias, float* __restrict__ C)
{
    __shared__ float As[BK][BM + 4];
    __shared__ float Bs[BK][BN + 4];

    const int tid = threadIdx.x;
    const int bx = blockIdx.x;
    const int by = blockIdx.y;

    const int arow = tid >> 1;
    const int acol = (tid & 1) * 4;
    const int brow = tid >> 5;
    const int bcol = (tid & 31) * 4;

    const int tx8 = (tid & 15) * 8;
    const int ty8 = (tid >> 4) * 8;

    float acc[8][8];
#pragma unroll
    for (int i = 0; i < 8; ++i)
#pragma unroll
        for (int j = 0; j < 8; ++j) acc[i][j] = 0.f;

    const unsigned short* Aptr =
        (const unsigned short*)A + (size_t)(by * BM + arow) * HH + acol;
    const float* Bptr = Bm + (size_t)brow * HH + bx * BN + bcol;

    for (int k0 = 0; k0 < HH; k0 += BK) {
        ushort4 au = *(const ushort4*)Aptr;
        float4 bv = *(const float4*)Bptr;
        As[acol + 0][arow] = bf2f(au.x);
        As[acol + 1][arow] = bf2f(au.y);
        As[acol + 2][arow] = bf2f(au.z);
        As[acol + 3][arow] = bf2f(au.w);
        *(float4*)&Bs[brow][bcol] = bv;
        __syncthreads();

#pragma unroll
        for (int k = 0; k < BK; ++k) {
            float a[8], bvv[8];
            *(float4*)&a[0] = *(const float4*)&As[k][ty8];
            *(float4*)&a[4] = *(const float4*)&As[k][ty8 + 4];
            *(float4*)&bvv[0] = *(const float4*)&Bs[k][tx8];
            *(float4*)&bvv[4] = *(const float4*)&Bs[k][tx8 + 4];
#pragma unroll
            for (int i = 0; i < 8; ++i)
#pragma unroll
                for (int j = 0; j < 8; ++j)
                    acc[i][j] += a[i] * bvv[j];
        }
        __syncthreads();
        Aptr += BK;
        Bptr += (size_t)BK * HH;
    }

    float bv8[8];
#pragma unroll
    for (int j = 0; j < 8; ++j) bv8[j] = bias[bx * BN + tx8 + j];

#pragma unroll
    for (int i = 0; i < 8; ++i) {
        float* cptr = C + (size_t)(by * BM + ty8 + i) * HH + bx * BN + tx8;
        float4 v0, v1;
        v0.x = acc[i][0] + bv8[0];
        v0.y = acc[i][1] + bv8[1];
        v0.z = acc[i][2] + bv8[2];
        v0.w = acc[i][3] + bv8[3];
        v1.x = acc[i][4] + bv8[4];
        v1.y = acc[i][5] + bv8[5];
        v1.z = acc[i][6] + bv8[6];
        v1.w = acc[i][7] + bv8[7];
        *(float4*)cptr = v0;
        *(float4*)(cptr + 4) = v1;
    }
}

// ---------------------------------------------------------------------------
extern "C" void kernel_launch(void* const* d_in, const int* in_sizes, int n_in,
                              void* d_out, int out_size, void* d_ws, size_t ws_size,
                              hipStream_t stream) {
    const float* x  = (const float*)d_in[0];   // [B, S, D]
    const float* Wg = (const float*)d_in[1];   // [D+H, 3H]
    const float* bg = (const float*)d_in[2];   // [3H]
    const float* Wc = (const float*)d_in[3];   // [H, O]
    const float* bc = (const float*)d_in[4];   // [O]
    float* out = (float*)d_out;                // [B, S, O]

    // Workspace layout (118.5 MB total):
    //   hs    : [B,S,H] bf16                       67,108,864 B
    //   Wt_hi : [2048*3072] bf16 fragment order    12,582,912 B
    //   Wt_lo : same                               12,582,912 B
    //   2 x state set {h fp32, h_hi bf16, h_lo bf16} = 2 x 524,288 B
    //   gx    : [TCH, B, 3H] fp32                  25,165,824 B
    char* ws = (char*)d_ws;
    __hip_bfloat16* hs = (__hip_bfloat16*)ws;
    short* Wt_hi = (short*)(ws + 67108864);
    short* Wt_lo = (short*)(ws + 67108864 + 12582912);
    char* state = ws + 67108864 + 2 * 12582912;
    const size_t SET = 524288;
    float* gx = (float*)(state + 2 * SET);

    float* hf[2];  short* hhi[2]; short* hlo[2];
    for (int p = 0; p < 2; ++p) {
        hf[p]  = (float*)(state + p * SET);
        hhi[p] = (short*)(state + p * SET + 262144);
        hlo[p] = (short*)(state + p * SET + 393216);
    }

    // zero the t=0 state set (fp32 h + hi + lo contiguous)
    hipMemsetAsync(state, 0, SET, stream);

    prep_w<<<3072, 256, 0, stream>>>(Wg, Wt_hi, Wt_lo);

    for (int t0 = 0; t0 < SS; t0 += TCH) {
        // hoisted, fully-parallel x-contribution for this chunk
        gx_gemm<<<TCH * 64, 256, 0, stream>>>(Wt_hi, Wt_lo, x, bg, gx, t0);
        for (int tl = 0; tl < TCH; ++tl) {
            int t = t0 + tl;
            int c = t & 1, n = c ^ 1;
            gru_step_h<<<256, 256, 0, stream>>>(
                Wt_hi, Wt_lo, gx,
                hf[c], hhi[c], hlo[c],
                hf[n], hhi[n], hlo[n],
                hs, t, tl);
        }
    }

    {
        dim3 g2(HH / BN, (BB * SS) / BM);
        out_gemm<<<g2, 256, 0, stream>>>(hs, Wc, bc, out);
    }
}

// Round 2
// 5517.735 us; speedup vs baseline: 3.7554x; 1.2237x over previous
//
#include <hip/hip_runtime.h>
#include <hip/hip_bf16.h>
#include <stdint.h>

// Problem constants: B=64, S=512, D=1024, H=1024, O=1024
#define BB   64
#define SS   512
#define DD   1024
#define HH   1024
#define TH3  3072   // 3*H
#define TCH  32     // timestep chunk for Gx precompute

using frag8 = __attribute__((ext_vector_type(8))) short;   // 8 bf16
using f32x4 = __attribute__((ext_vector_type(4))) float;

__device__ __forceinline__ void split_bf16(float v, short& hi, short& lo) {
    uint32_t u = __float_as_uint(v);
    uint32_t uh = u & 0xFFFF0000u;          // truncate to bf16
    float fl = v - __uint_as_float(uh);     // exact residual
    hi = (short)(uh >> 16);
    lo = (short)(__float_as_uint(fl) >> 16);
}

// ---------------------------------------------------------------------------
// W pre-transform: Wg [2048, 3072] fp32 -> Wt_hi/Wt_lo bf16 in MFMA B-fragment
// order. Fragment f = (jb*3 + g)*64 + kt covers k = kt*32 + quad*8 + j,
// n(col) = g*1024 + jb*16 + (lane&15). Stored as Wt[f*512 + lane*8 + j].
// kt 0..31 = x rows (0..1023), kt 32..63 = h rows (1024..2047).
// ---------------------------------------------------------------------------
__global__ __launch_bounds__(256) void prep_w(
    const float* __restrict__ Wg, short* __restrict__ Wt_hi,
    short* __restrict__ Wt_lo)
{
    int idx = blockIdx.x * 256 + threadIdx.x;   // 0 .. 786431
    int lane = idx & 63;
    int f = idx >> 6;            // 0..12287
    int kt = f & 63;
    int fg = f >> 6;
    int g = fg % 3;
    int jb = fg / 3;
    int krow = kt * 32 + (lane >> 4) * 8;
    int col = g * HH + jb * 16 + (lane & 15);
    size_t dst = (size_t)f * 512 + (size_t)lane * 8;
#pragma unroll
    for (int j = 0; j < 8; ++j) {
        float v = Wg[(size_t)(krow + j) * TH3 + col];
        short hi, lo;
        split_bf16(v, hi, lo);
        Wt_hi[dst + j] = hi;
        Wt_lo[dst + j] = lo;
    }
}

// ---------------------------------------------------------------------------
// Wc pre-transform: Wc [1024,1024] fp32 -> B-fragment order, f = jb*32 + kt.
// ---------------------------------------------------------------------------
__global__ __launch_bounds__(256) void prep_wc(
    const float* __restrict__ Wc, short* __restrict__ Wct_hi,
    short* __restrict__ Wct_lo)
{
    int idx = blockIdx.x * 256 + threadIdx.x;   // 0 .. 131071
    int lane = idx & 63;
    int f = idx >> 6;            // 0..2047
    int kt = f & 31;
    int jb = f >> 5;
    int krow = kt * 32 + (lane >> 4) * 8;
    int col = jb * 16 + (lane & 15);
    size_t dst = (size_t)f * 512 + (size_t)lane * 8;
#pragma unroll
    for (int j = 0; j < 8; ++j) {
        float v = Wc[(size_t)(krow + j) * HH + col];
        short hi, lo;
        split_bf16(v, hi, lo);
        Wct_hi[dst + j] = hi;
        Wct_lo[dst + j] = lo;
    }
}

// ---------------------------------------------------------------------------
// Gx precompute: gx[tl, m, :] = x[m, t0+tl, :] @ Wg[0:1024, :] + bg
// Grid = 32 tl x 16 jbg (jbg fastest, stride 16 -> same-jbg same XCD so the
// W slice stays L2-resident across tl). 4 waves: wave w covers m-rows
// (w&1)*32..+31 (2 m-frags) x 2 jb ((w>>1)*2 within the jbg's 4). The x
// split_bf16 is amortized over 2 jb x 3 gates, and each B fragment feeds
// 2 m-frags (halved B traffic vs 1-frag waves).
// ---------------------------------------------------------------------------
__global__ __launch_bounds__(256) void gx_gemm(
    const short* __restrict__ Wt_hi, const short* __restrict__ Wt_lo,
    const float* __restrict__ x,        // [B, S, D] fp32
    const float* __restrict__ bg,       // [3H]
    float* __restrict__ gx,             // [TCH, B, 3H] fp32
    int t0)
{
    const int tid = threadIdx.x;
    const int lane = tid & 63;
    const int w = tid >> 6;
    const int jbg = blockIdx.x & 15;
    const int tl = blockIdx.x >> 4;
    const int t = t0 + tl;
    const int m0 = (w & 1) * 32;
    const int jbb = jbg * 4 + (w >> 1) * 2;
    const int kq = (lane >> 4) * 8;

    f32x4 acc[2][2][3];
#pragma unroll
    for (int mi = 0; mi < 2; ++mi)
#pragma unroll
        for (int jp = 0; jp < 2; ++jp)
#pragma unroll
            for (int g = 0; g < 3; ++g)
                acc[mi][jp][g] = (f32x4){0.f, 0.f, 0.f, 0.f};

    const float* xr0 = x + ((size_t)(m0 + (lane & 15)) * SS + t) * DD;
    const float* xr1 = xr0 + (size_t)16 * SS * DD;

    for (int kt = 0; kt < 32; ++kt) {
        frag8 ah[2], al[2];
#pragma unroll
        for (int mi = 0; mi < 2; ++mi) {
            const float* xp = (mi == 0 ? xr0 : xr1) + kt * 32 + kq;
            float xv[8];
            *(float4*)&xv[0] = *(const float4*)xp;
            *(float4*)&xv[4] = *(const float4*)(xp + 4);
#pragma unroll
            for (int j = 0; j < 8; ++j) {
                short hi, lo;
                split_bf16(xv[j], hi, lo);
                ah[mi][j] = hi;
                al[mi][j] = lo;
            }
        }
#pragma unroll
        for (int jp = 0; jp < 2; ++jp) {
#pragma unroll
            for (int g = 0; g < 3; ++g) {
                size_t base =
                    (((size_t)(jbb + jp) * 3 + g) * 64 + kt) * 512 + (size_t)lane * 8;
                frag8 bh = *(const frag8*)(Wt_hi + base);
                frag8 bl = *(const frag8*)(Wt_lo + base);
#pragma unroll
                for (int mi = 0; mi < 2; ++mi) {
                    f32x4 a = acc[mi][jp][g];
                    a = __builtin_amdgcn_mfma_f32_16x16x32_bf16(ah[mi], bh, a, 0, 0, 0);
                    a = __builtin_amdgcn_mfma_f32_16x16x32_bf16(ah[mi], bl, a, 0, 0, 0);
                    a = __builtin_amdgcn_mfma_f32_16x16x32_bf16(al[mi], bh, a, 0, 0, 0);
                    acc[mi][jp][g] = a;
                }
            }
        }
    }

    const int lcol = lane & 15;
    const int rq = (lane >> 4) * 4;
#pragma unroll
    for (int jp = 0; jp < 2; ++jp) {
        const int col = (jbb + jp) * 16 + lcol;
#pragma unroll
        for (int g = 0; g < 3; ++g) {
            const float bias = bg[g * HH + col];
#pragma unroll
            for (int mi = 0; mi < 2; ++mi) {
#pragma unroll
                for (int reg = 0; reg < 4; ++reg) {
                    int m = m0 + mi * 16 + rq + reg;
                    gx[((size_t)tl * BB + m) * TH3 + g * HH + col] =
                        acc[mi][jp][g][reg] + bias;
                }
            }
        }
    }
}

// ---------------------------------------------------------------------------
// One GRU step, h-contribution only: gates = gx[tl] + h @ Wg[1024:2048, :].
// Grid = 256 blocks = 4 m-tiles x 64 jb (jb fastest -> same-jb same XCD).
// 4 waves K-split the 32 kt (8 each), partials reduced through LDS; the
// 256 threads then each own one of the 16x16 outputs for the epilogue.
// ---------------------------------------------------------------------------
__global__ __launch_bounds__(256) void gru_step_h(
    const short* __restrict__ Wt_hi, const short* __restrict__ Wt_lo,
    const float* __restrict__ gx,       // [TCH, B, 3H]
    const float* __restrict__ h_f,      // [B, H] fp32 (current)
    const short* __restrict__ h_hi,     // [B, H] bf16 hi (current)
    const short* __restrict__ h_lo,     // [B, H] bf16 lo (current)
    float* __restrict__ hn_f,           // [B, H] fp32 (next)
    short* __restrict__ hn_hi, short* __restrict__ hn_lo,
    __hip_bfloat16* __restrict__ hs,    // [B, S, H] bf16 history
    int t, int tl)
{
    __shared__ float red[12][256];      // [w*3+g][lane*4+reg]

    const int tid = threadIdx.x;
    const int lane = tid & 63;
    const int w = tid >> 6;
    const int jb = blockIdx.x & 63;
    const int mt = blockIdx.x >> 6;
    const int m0 = mt * 16;
    const int mrow = m0 + (lane & 15);
    const int kq = (lane >> 4) * 8;

    // Hoisted epilogue loads: issue before the MFMA loop so their latency
    // hides under compute. Thread tid owns output (lv=tid>>2, reg=tid&3).
    const int lv = tid >> 2;
    const int reg = tid & 3;
    const int ecol = jb * 16 + (lv & 15);
    const int em = m0 + ((lv >> 4) << 2) + reg;
    const float* gp = gx + ((size_t)tl * BB + em) * TH3 + ecol;
    const float gxr = gp[0];
    const float gxz = gp[HH];
    const float gxn = gp[2 * HH];
    const float hold = h_f[(size_t)em * HH + ecol];

    f32x4 accr = {0.f, 0.f, 0.f, 0.f};
    f32x4 accz = {0.f, 0.f, 0.f, 0.f};
    f32x4 accn = {0.f, 0.f, 0.f, 0.f};
    const size_t fbase = (size_t)jb * 3 * 64;
    const short* hrh = h_hi + (size_t)mrow * HH;
    const short* hrl = h_lo + (size_t)mrow * HH;

#pragma unroll
    for (int i = 0; i < 8; ++i) {
        const int kt = w * 8 + i;                  // this wave's K slice
        frag8 a_hi = *(const frag8*)(hrh + kt * 32 + kq);
        frag8 a_lo = *(const frag8*)(hrl + kt * 32 + kq);
#pragma unroll
        for (int g = 0; g < 3; ++g) {
            size_t base = (fbase + (size_t)g * 64 + 32 + kt) * 512 + (size_t)lane * 8;
            frag8 b_hi = *(const frag8*)(Wt_hi + base);
            frag8 b_lo = *(const frag8*)(Wt_lo + base);
            f32x4 acc = (g == 0) ? accr : (g == 1) ? accz : accn;
            acc = __builtin_amdgcn_mfma_f32_16x16x32_bf16(a_hi, b_hi, acc, 0, 0, 0);
            acc = __builtin_amdgcn_mfma_f32_16x16x32_bf16(a_hi, b_lo, acc, 0, 0, 0);
            acc = __builtin_amdgcn_mfma_f32_16x16x32_bf16(a_lo, b_hi, acc, 0, 0, 0);
            if (g == 0) accr = acc; else if (g == 1) accz = acc; else accn = acc;
        }
    }

    *(f32x4*)&red[w * 3 + 0][lane * 4] = accr;
    *(f32x4*)&red[w * 3 + 1][lane * 4] = accz;
    *(f32x4*)&red[w * 3 + 2][lane * 4] = accn;
    __syncthreads();

    // Cross-wave K reduction (stride-1 in tid: conflict-free).
    float rg = gxr + red[0][tid] + red[3][tid] + red[6][tid] + red[9][tid];
    float zg = gxz + red[1][tid] + red[4][tid] + red[7][tid] + red[10][tid];
    float ng = gxn + red[2][tid] + red[5][tid] + red[8][tid] + red[11][tid];

    float r = 1.f / (1.f + __expf(-rg));
    float z = 1.f / (1.f + __expf(-zg));
    float na = ng + r * hold;
    float n = 1.f - 2.f / (1.f + __expf(2.f * na));   // tanh(na)
    float hn = (1.f - z) * n + z * hold;

    hn_f[(size_t)em * HH + ecol] = hn;
    short hi, lo;
    split_bf16(hn, hi, lo);
    hn_hi[(size_t)em * HH + ecol] = hi;
    hn_lo[(size_t)em * HH + ecol] = lo;
    hs[((size_t)em * SS + t) * HH + ecol] = __float2bfloat16(hn);
}

// ---------------------------------------------------------------------------
// Output GEMM via MFMA: out[B*S, O] = hs_bf16 @ (Wc_hi + Wc_lo) + bc.
// Block = 128x128 tile, 2x2 waves; each wave 4 m-frags x 4 jb, full K.
// Grid = 256 mb x 8 nb (nb fastest, stride 8 -> same-nb same XCD: the
// 524 KB Wct slice per nb stays L2-resident).
// ---------------------------------------------------------------------------
__global__ __launch_bounds__(256) void out_mfma(
    const short* __restrict__ Wct_hi, const short* __restrict__ Wct_lo,
    const __hip_bfloat16* __restrict__ hs,   // [B*S, H] bf16
    const float* __restrict__ bc, float* __restrict__ out)
{
    const int tid = threadIdx.x;
    const int lane = tid & 63;
    const int w = tid >> 6;
    const int nb = blockIdx.x & 7;
    const int mb = blockIdx.x >> 3;
    const int r0 = mb * 128 + (w & 1) * 64;     // wave row base
    const int jb0 = nb * 8 + (w >> 1) * 4;      // wave global-jb base
    const int kq = (lane >> 4) * 8;

    f32x4 acc[4][4];
#pragma unroll
    for (int i = 0; i < 4; ++i)
#pragma unroll
        for (int j = 0; j < 4; ++j) acc[i][j] = (f32x4){0.f, 0.f, 0.f, 0.f};

    const short* ar[4];
#pragma unroll
    for (int i = 0; i < 4; ++i)
        ar[i] = (const short*)hs +
                (size_t)(r0 + i * 16 + (lane & 15)) * HH + kq;

    for (int kt = 0; kt < 32; ++kt) {
        frag8 a[4];
#pragma unroll
        for (int i = 0; i < 4; ++i)
            a[i] = *(const frag8*)(ar[i] + kt * 32);
#pragma unroll
        for (int j = 0; j < 4; ++j) {
            size_t base = ((size_t)(jb0 + j) * 32 + kt) * 512 + (size_t)lane * 8;
            frag8 bh = *(const frag8*)(Wct_hi + base);
            frag8 bl = *(const frag8*)(Wct_lo + base);
#pragma unroll
            for (int i = 0; i < 4; ++i) {
                acc[i][j] = __builtin_amdgcn_mfma_f32_16x16x32_bf16(a[i], bh, acc[i][j], 0, 0, 0);
                acc[i][j] = __builtin_amdgcn_mfma_f32_16x16x32_bf16(a[i], bl, acc[i][j], 0, 0, 0);
            }
        }
    }

    const int lcol = lane & 15;
    const int rq = (lane >> 4) * 4;
#pragma unroll
    for (int j = 0; j < 4; ++j) {
        const int col = (jb0 + j) * 16 + lcol;
        const float bias = bc[col];
#pragma unroll
        for (int i = 0; i < 4; ++i) {
#pragma unroll
            for (int reg = 0; reg < 4; ++reg) {
                int row = r0 + i * 16 + rq + reg;
                out[(size_t)row * HH + col] = acc[i][j][reg] + bias;
            }
        }
    }
}

// ---------------------------------------------------------------------------
extern "C" void kernel_launch(void* const* d_in, const int* in_sizes, int n_in,
                              void* d_out, int out_size, void* d_ws, size_t ws_size,
                              hipStream_t stream) {
    const float* x  = (const float*)d_in[0];   // [B, S, D]
    const float* Wg = (const float*)d_in[1];   // [D+H, 3H]
    const float* bg = (const float*)d_in[2];   // [3H]
    const float* Wc = (const float*)d_in[3];   // [H, O]
    const float* bc = (const float*)d_in[4];   // [O]
    float* out = (float*)d_out;                // [B, S, O]

    // Workspace layout (118.5 MB total):
    //   hs    : [B,S,H] bf16                       67,108,864 B
    //   Wt_hi : [2048*3072] bf16 fragment order    12,582,912 B
    //   Wt_lo : same                               12,582,912 B
    //   2 x state set {h fp32, h_hi bf16, h_lo bf16} = 2 x 524,288 B
    //   gx    : [TCH, B, 3H] fp32                  25,165,824 B
    //   Wct_hi/Wct_lo (2 MB each) alias the gx buffer — gx is dead by the
    //   time prep_wc runs (after the recurrence loop).
    char* ws = (char*)d_ws;
    __hip_bfloat16* hs = (__hip_bfloat16*)ws;
    short* Wt_hi = (short*)(ws + 67108864);
    short* Wt_lo = (short*)(ws + 67108864 + 12582912);
    char* state = ws + 67108864 + 2 * 12582912;
    const size_t SET = 524288;
    float* gx = (float*)(state + 2 * SET);
    short* Wct_hi = (short*)gx;                  // aliases gx (post-loop only)
    short* Wct_lo = Wct_hi + 1048576;

    float* hf[2];  short* hhi[2]; short* hlo[2];
    for (int p = 0; p < 2; ++p) {
        hf[p]  = (float*)(state + p * SET);
        hhi[p] = (short*)(state + p * SET + 262144);
        hlo[p] = (short*)(state + p * SET + 393216);
    }

    // zero the t=0 state set (fp32 h + hi + lo contiguous)
    hipMemsetAsync(state, 0, SET, stream);

    prep_w<<<3072, 256, 0, stream>>>(Wg, Wt_hi, Wt_lo);

    for (int t0 = 0; t0 < SS; t0 += TCH) {
        // hoisted, fully-parallel x-contribution for this chunk
        gx_gemm<<<512, 256, 0, stream>>>(Wt_hi, Wt_lo, x, bg, gx, t0);
        for (int tl = 0; tl < TCH; ++tl) {
            int t = t0 + tl;
            int c = t & 1, n = c ^ 1;
            gru_step_h<<<256, 256, 0, stream>>>(
                Wt_hi, Wt_lo, gx,
                hf[c], hhi[c], hlo[c],
                hf[n], hhi[n], hlo[n],
                hs, t, tl);
        }
    }

    {
        prep_wc<<<512, 256, 0, stream>>>(Wc, Wct_hi, Wct_lo);
        out_mfma<<<2048, 256, 0, stream>>>(Wct_hi, Wct_lo, hs, bc, out);
    }
}